// Round 2
// baseline (108.827 us; speedup 1.0000x reference)
//
#include <hip/hip_runtime.h>
#include <math.h>

#define B_ROWS 8192
#define NPROTO 10
#define NCLS 10
#define NPATCH 196

// workspace layout (floats)
#define TABLE_OFF 0                               // 80 floats: per proto [cy0..3, sy0..3]
#define WT2_OFF   80                              // transposed weights [p][proto][c]
#define WT2_ELEMS (NPATCH * NPROTO * NCLS)        // 19600 floats
#define WS_NEEDED ((size_t)(WT2_OFF + WT2_ELEMS) * sizeof(float))

// ---------- prep: sincos table, weight transpose, zero the logit accumulator ----------
__global__ __launch_bounds__(256) void quanv_prep(
    const float* __restrict__ W, const float* __restrict__ protos,
    float* __restrict__ ws, float* __restrict__ out, int buildWt2) {
  int idx = blockIdx.x * 256 + threadIdx.x;
  if (idx < NPROTO * 8) {
    int proto = idx >> 3;
    int j = idx & 7;
    float h = 0.5f * protos[proto * 4 + (j & 3)];
    ws[TABLE_OFF + idx] = (j < 4) ? __cosf(h) : __sinf(h);
  }
  if (buildWt2 && idx < WT2_ELEMS) {
    int p     = idx / (NPROTO * NCLS);
    int rem   = idx - p * (NPROTO * NCLS);
    int proto = rem / NCLS;
    int c     = rem - proto * NCLS;
    ws[WT2_OFF + idx] = W[c * (NPROTO * NPATCH) + proto * NPATCH + p];
  }
  if (idx < B_ROWS * NCLS) out[idx] = 0.0f;   // zero logit accumulator
}

// ---------- main: lanes = rows, patch index wave-uniform -> scalar weight loads ----------
template <bool USE_WT2>
__global__ __launch_bounds__(256) void quanv_main(
    const float* __restrict__ x, const float* __restrict__ ws,
    const float* __restrict__ W, float* __restrict__ out) {
  __shared__ float red[64 * NCLS];   // 2.56 KB

  const int tid = threadIdx.x;
  for (int i = tid; i < 64 * NCLS; i += 256) red[i] = 0.0f;
  __syncthreads();

  // readfirstlane makes wid provably wave-uniform -> patch index p uniform -> s_load weights
  const int wid  = __builtin_amdgcn_readfirstlane(tid >> 6);
  const int lane = tid & 63;
  const int r    = blockIdx.x * 64 + lane;   // this lane's row
  const int pr   = blockIdx.y;               // patch-row 0..13

  const float* tb  = ws + TABLE_OFF;   // uniform
  const float* Wt2 = ws + WT2_OFF;     // uniform

  const int pj0 = (wid < 2) ? wid * 4 : 8 + (wid - 2) * 3;  // 0,4,8,11
  const int npj = (wid < 2) ? 4 : 3;

  float acc[NCLS];
#pragma unroll
  for (int c = 0; c < NCLS; ++c) acc[c] = 0.0f;

  const float* xr = x + (size_t)r * 784 + pr * 56;

  for (int j = 0; j < npj; ++j) {
    int pj = pj0 + j;
    int p  = pr * 14 + pj;                 // wave-uniform
    float2 a01 = *(const float2*)(xr + 2 * pj);
    float2 a23 = *(const float2*)(xr + 2 * pj + 28);
    float s0, c0, s1, c1, s2, c2, s3, c3;
    __sincosf(0.5f * a01.x, &s0, &c0);
    __sincosf(0.5f * a01.y, &s1, &c1);
    __sincosf(0.5f * a23.x, &s2, &c2);
    __sincosf(0.5f * a23.y, &s3, &c3);

#pragma unroll
    for (int proto = 0; proto < NPROTO; ++proto) {
      const float* t8 = tb + proto * 8;                 // uniform -> s_load
      float t0 = fmaf(c0, t8[0], s0 * t8[4]);
      float t1 = fmaf(c1, t8[1], s1 * t8[5]);
      float t2 = fmaf(c2, t8[2], s2 * t8[6]);
      float t3 = fmaf(c3, t8[3], s3 * t8[7]);
      float q  = fabsf((t0 * t1) * (t2 * t3));
#pragma unroll
      for (int c = 0; c < NCLS; ++c) {
        float w = USE_WT2 ? Wt2[p * (NPROTO * NCLS) + proto * NCLS + c]
                          : W[c * (NPROTO * NPATCH) + proto * NPATCH + p];  // uniform either way
        acc[c] = fmaf(q, w, acc[c]);
      }
    }
  }

  // in-block reduction across the 4 waves (same 64 rows)
#pragma unroll
  for (int c = 0; c < NCLS; ++c) atomicAdd(&red[lane * NCLS + c], acc[c]);
  __syncthreads();

  // one global atomic per (row, class) per block (14 blocks contend per address)
  for (int i = tid; i < 64 * NCLS; i += 256) {
    atomicAdd(&out[(size_t)blockIdx.x * 64 * NCLS + i], red[i]);
  }
}

// ---------- epilogue: bias + log_softmax in place ----------
__global__ __launch_bounds__(256) void quanv_softmax(
    float* __restrict__ out, const float* __restrict__ bias) {
  int r = blockIdx.x * 256 + threadIdx.x;  // 8192 threads
  float v[NCLS];
  float m = -1e30f;
#pragma unroll
  for (int c = 0; c < NCLS; ++c) {
    v[c] = out[r * NCLS + c] + bias[c];
    m = fmaxf(m, v[c]);
  }
  float sum = 0.0f;
#pragma unroll
  for (int c = 0; c < NCLS; ++c) sum += __expf(v[c] - m);
  float lse = m + __logf(sum);
#pragma unroll
  for (int c = 0; c < NCLS; ++c) out[r * NCLS + c] = v[c] - lse;
}

extern "C" void kernel_launch(void* const* d_in, const int* in_sizes, int n_in,
                              void* d_out, int out_size, void* d_ws, size_t ws_size,
                              hipStream_t stream) {
  const float* x      = (const float*)d_in[0];
  const float* protos = (const float*)d_in[1];
  const float* W      = (const float*)d_in[2];
  const float* bias   = (const float*)d_in[3];
  float* out = (float*)d_out;
  float* ws  = (float*)d_ws;

  const bool useWt2 = (ws_size >= WS_NEEDED);

  quanv_prep<<<(B_ROWS * NCLS + 255) / 256, 256, 0, stream>>>(W, protos, ws, out, useWt2 ? 1 : 0);

  dim3 grid(B_ROWS / 64, 14);
  if (useWt2)
    quanv_main<true><<<grid, 256, 0, stream>>>(x, ws, W, out);
  else
    quanv_main<false><<<grid, 256, 0, stream>>>(x, ws, W, out);

  quanv_softmax<<<B_ROWS / 256, 256, 0, stream>>>(out, bias);
}

// Round 3
// 91.344 us; speedup vs baseline: 1.1914x; 1.1914x over previous
//
#include <hip/hip_runtime.h>
#include <math.h>

#define B_ROWS 8192
#define NPROTO 10
#define NCLS   10
#define NPATCH 196

// workspace layout (floats)
#define TABLE_OFF 0                         // 80: per proto [cy0..3, sy0..3]
#define WT2_OFF   128                       // 19600: [p][proto][c]
#define PART_OFF  19776                     // 7*8192*10 partial logits
#define XS_STRIDE 113                       // 113%32=17, gcd(17,32)=1 -> conflict-free

// ---------- prep: sincos table + weight transpose ----------
__global__ __launch_bounds__(256) void quanv_prep(
    const float* __restrict__ W, const float* __restrict__ protos,
    float* __restrict__ ws) {
  int idx = blockIdx.x * 256 + threadIdx.x;
  if (idx < NPROTO * 8) {
    int proto = idx >> 3;
    int j = idx & 7;
    float h = 0.5f * protos[proto * 4 + (j & 3)];
    ws[TABLE_OFF + idx] = (j < 4) ? __cosf(h) : __sinf(h);
  }
  if (idx < NPATCH * NPROTO * NCLS) {
    int p     = idx / (NPROTO * NCLS);
    int rem   = idx - p * (NPROTO * NCLS);
    int proto = rem / NCLS;
    int c     = rem - proto * NCLS;
    ws[WT2_OFF + idx] = W[c * (NPROTO * NPATCH) + proto * NPATCH + p];
  }
}

// ---------- main: LDS-transposed x (coalesced fetch) + scalar weights ----------
__global__ __launch_bounds__(256) void quanv_main(
    const float* __restrict__ x, const float* __restrict__ ws,
    float* __restrict__ partial) {
  __shared__ float xs[64 * XS_STRIDE];      // 28.9 KB
  __shared__ float red[4 * 64 * 11];        // 11.3 KB (stride 11: conflict-free)

  const int tid = threadIdx.x;
  const int bx  = blockIdx.x;               // row group (64 rows)
  const int pr2 = blockIdx.y;               // pair of patch-rows, 0..6

  // Stage 64 rows x 112 floats (image rows 4*pr2..4*pr2+3), coalesced float4.
  {
    const float* src = x + (size_t)bx * 64 * 784 + pr2 * 112;
    for (int i = tid; i < 64 * 28; i += 256) {
      int row = i / 28, quad = i - row * 28;
      float4 v = *(const float4*)(src + (size_t)row * 784 + quad * 4);
      float* d = &xs[row * XS_STRIDE + quad * 4];
      d[0] = v.x; d[1] = v.y; d[2] = v.z; d[3] = v.w;
    }
  }
  __syncthreads();

  // readfirstlane -> provably wave-uniform patch index -> s_load weights
  const int wid  = __builtin_amdgcn_readfirstlane(tid >> 6);
  const int lane = tid & 63;                // lane = row within group
  const float* tb  = ws + TABLE_OFF;
  const float* Wt2 = ws + WT2_OFF;
  const float* xr  = &xs[lane * XS_STRIDE];

  float acc[NCLS];
#pragma unroll
  for (int c = 0; c < NCLS; ++c) acc[c] = 0.0f;

  for (int j = 0; j < 7; ++j) {             // 28 patches / 4 waves = 7 each
    int lp  = wid * 7 + j;                  // local patch 0..27 (uniform)
    int piL = lp >= 14 ? 1 : 0;
    int pj  = lp - piL * 14;
    int off = piL * 56 + 2 * pj;
    float x0 = xr[off],      x1 = xr[off + 1];
    float x2 = xr[off + 28], x3 = xr[off + 29];
    float s0, c0, s1, c1, s2, c2, s3, c3;
    __sincosf(0.5f * x0, &s0, &c0);
    __sincosf(0.5f * x1, &s1, &c1);
    __sincosf(0.5f * x2, &s2, &c2);
    __sincosf(0.5f * x3, &s3, &c3);

    int p = pr2 * 28 + lp;                  // global patch index (uniform)
    const float* wp = Wt2 + p * (NPROTO * NCLS);
#pragma unroll
    for (int proto = 0; proto < NPROTO; ++proto) {
      const float* t8 = tb + proto * 8;     // uniform -> scalar loads
      float t0 = fmaf(c0, t8[0], s0 * t8[4]);
      float t1 = fmaf(c1, t8[1], s1 * t8[5]);
      float t2 = fmaf(c2, t8[2], s2 * t8[6]);
      float t3 = fmaf(c3, t8[3], s3 * t8[7]);
      float q  = fabsf((t0 * t1) * (t2 * t3));
      const float* wq = wp + proto * NCLS;  // uniform -> scalar loads
#pragma unroll
      for (int c = 0; c < NCLS; ++c) acc[c] = fmaf(q, wq[c], acc[c]);
    }
  }

  // cross-wave reduction in LDS (plain writes + tree, no atomics)
  {
    float* myred = &red[(tid >> 6) * (64 * 11) + lane * 11];
#pragma unroll
    for (int c = 0; c < NCLS; ++c) myred[c] = acc[c];
  }
  __syncthreads();

  for (int i = tid; i < 64 * NCLS; i += 256) {
    int row = i / NCLS, c = i - row * NCLS;
    int o = row * 11 + c;
    float s = red[o] + red[704 + o] + red[1408 + o] + red[2112 + o];
    partial[((size_t)pr2 * B_ROWS + (size_t)bx * 64 + row) * NCLS + c] = s;
  }
}

// ---------- final: sum 7 partials + bias + log_softmax ----------
__global__ __launch_bounds__(256) void quanv_final(
    const float* __restrict__ partial, const float* __restrict__ bias,
    float* __restrict__ out) {
  int r = blockIdx.x * 256 + threadIdx.x;
  float v[NCLS];
#pragma unroll
  for (int c = 0; c < NCLS; ++c) v[c] = bias[c];
  for (int y = 0; y < 7; ++y) {
    const float* pp = partial + ((size_t)y * B_ROWS + r) * NCLS;
#pragma unroll
    for (int c = 0; c < NCLS; c += 2) {     // 8B-aligned float2 loads
      float2 t = *(const float2*)(pp + c);
      v[c] += t.x; v[c + 1] += t.y;
    }
  }
  float m = v[0];
#pragma unroll
  for (int c = 1; c < NCLS; ++c) m = fmaxf(m, v[c]);
  float sum = 0.0f;
#pragma unroll
  for (int c = 0; c < NCLS; ++c) sum += __expf(v[c] - m);
  float lse = m + __logf(sum);
#pragma unroll
  for (int c = 0; c < NCLS; ++c) out[r * NCLS + c] = v[c] - lse;
}

extern "C" void kernel_launch(void* const* d_in, const int* in_sizes, int n_in,
                              void* d_out, int out_size, void* d_ws, size_t ws_size,
                              hipStream_t stream) {
  const float* x      = (const float*)d_in[0];
  const float* protos = (const float*)d_in[1];
  const float* W      = (const float*)d_in[2];
  const float* bias   = (const float*)d_in[3];
  float* out = (float*)d_out;
  float* ws  = (float*)d_ws;

  quanv_prep<<<(NPATCH * NPROTO * NCLS + 255) / 256, 256, 0, stream>>>(W, protos, ws);
  quanv_main<<<dim3(B_ROWS / 64, 7), 256, 0, stream>>>(x, ws, ws + PART_OFF);
  quanv_final<<<B_ROWS / 256, 256, 0, stream>>>(ws + PART_OFF, bias, out);
}